// Round 7
// baseline (423.756 us; speedup 1.0000x reference)
//
#include <hip/hip_runtime.h>

#define NN 50000
#define IN_DIM 128
#define HID 64
#define NLAYERS 3
#define PART_SZ 6250  // NN/8 — one contiguous node range per XCD (blockIdx&7)

typedef __attribute__((ext_vector_type(8))) short bf16x8;
typedef __attribute__((ext_vector_type(4))) float f32x4;

__device__ __forceinline__ unsigned f2bf(float f) {
    unsigned u = __float_as_uint(f);
    return (u + 0x7fffu + ((u >> 16) & 1u)) >> 16;  // round-to-nearest-even
}

// Pack two fp32 -> packed bf16 pair (a -> lo, b -> hi), round-half-up.
__device__ __forceinline__ unsigned pk2bf(float a, float b) {
    return __builtin_amdgcn_perm(__float_as_uint(b) + 0x8000u,
                                 __float_as_uint(a) + 0x8000u, 0x07060302u);
}

// q = packed bf16 pair. Returns packed bf16 pair of relu(q + p).
__device__ __forceinline__ unsigned pack_r(unsigned q, float pA, float pB) {
    float lo = fmaxf(__uint_as_float(q << 16) + pA, 0.f);
    float hi = fmaxf(__uint_as_float(q & 0xffff0000u) + pB, 0.f);
    return pk2bf(lo, hi);
}

__global__ void k_zero(int* __restrict__ p, int n) {
    int i = blockIdx.x * blockDim.x + threadIdx.x;
    if (i < n) p[i] = 0;
}

// Partitioned degree count: block b handles dst range [(b&7)*PART_SZ, +PART_SZ).
__global__ void __launch_bounds__(256) k_count_part(const int* __restrict__ dst,
                                                    int* __restrict__ deg, int E) {
    int lo = (blockIdx.x & 7) * PART_SZ, hi = lo + PART_SZ;
    int stride = (gridDim.x >> 3) * 256;
    for (int e = (blockIdx.x >> 3) * 256 + threadIdx.x; e < E; e += stride) {
        int d = dst[e];
        if (d >= lo && d < hi) atomicAdd(&deg[d], 1);
    }
}

// 3-kernel exclusive scan over deg[N] -> off[N]
__global__ void k_scan_partial(const int* __restrict__ deg, int* __restrict__ part, int n) {
    __shared__ int s[256];
    int i = blockIdx.x * 256 + threadIdx.x;
    s[threadIdx.x] = (i < n) ? deg[i] : 0;
    __syncthreads();
    for (int d = 128; d > 0; d >>= 1) {
        if (threadIdx.x < d) s[threadIdx.x] += s[threadIdx.x + d];
        __syncthreads();
    }
    if (threadIdx.x == 0) part[blockIdx.x] = s[0];
}

__global__ void k_scan_root(int* part, int nb) {
    __shared__ int s[256];
    int t = threadIdx.x;
    int v = (t < nb) ? part[t] : 0;
    s[t] = v;
    __syncthreads();
    for (int d = 1; d < 256; d <<= 1) {
        int add = (t >= d) ? s[t - d] : 0;
        __syncthreads();
        s[t] += add;
        __syncthreads();
    }
    if (t < nb) part[t] = s[t] - v;
}

__global__ void k_scan_final(const int* __restrict__ deg, const int* __restrict__ part,
                             int* __restrict__ off, int n) {
    __shared__ int s[256];
    int t = threadIdx.x;
    int i = blockIdx.x * 256 + t;
    int v = (i < n) ? deg[i] : 0;
    s[t] = v;
    __syncthreads();
    for (int d = 1; d < 256; d <<= 1) {
        int add = (t >= d) ? s[t - d] : 0;
        __syncthreads();
        s[t] += add;
        __syncthreads();
    }
    if (i < n) off[i] = part[blockIdx.x] + s[t] - v;
}

// Partitioned scatter into ushort CSR; same block->range mapping as count.
__global__ void __launch_bounds__(256) k_scatter_part(
    const int* __restrict__ src, const int* __restrict__ dst,
    const int* __restrict__ off, int* __restrict__ cursor,
    unsigned short* __restrict__ csr, int E) {
    int lo = (blockIdx.x & 7) * PART_SZ, hi = lo + PART_SZ;
    int stride = (gridDim.x >> 3) * 256;
    for (int e = (blockIdx.x >> 3) * 256 + threadIdx.x; e < E; e += stride) {
        int d = dst[e];
        if (d >= lo && d < hi) {
            int pos = atomicAdd(&cursor[d], 1);
            csr[off[d] + pos] = (unsigned short)src[e];
        }
    }
}

// h = x @ Wp + bp. Wave handles 4 nodes; weight loads amortized 4x.
__global__ void k_proj4(const float* __restrict__ x, const float* __restrict__ Wp,
                        const float* __restrict__ bp, float* __restrict__ h) {
    __shared__ float xs[4][4][IN_DIM];
    int lane = threadIdx.x & 63, wave = threadIdx.x >> 6;
    int node0 = blockIdx.x * 16 + wave * 4;
#pragma unroll
    for (int n = 0; n < 4; n++) {
        xs[wave][n][lane]      = x[(size_t)(node0 + n) * IN_DIM + lane];
        xs[wave][n][64 + lane] = x[(size_t)(node0 + n) * IN_DIM + 64 + lane];
    }
    __syncthreads();
    float bv = bp[lane];
    float acc[4] = {bv, bv, bv, bv};
#pragma unroll
    for (int k = 0; k < IN_DIM; k += 4) {
        float w0 = Wp[(k + 0) * HID + lane];
        float w1 = Wp[(k + 1) * HID + lane];
        float w2 = Wp[(k + 2) * HID + lane];
        float w3 = Wp[(k + 3) * HID + lane];
#pragma unroll
        for (int n = 0; n < 4; n++) {
            float4 xv = *(const float4*)&xs[wave][n][k];
            acc[n] = fmaf(xv.x, w0, acc[n]);
            acc[n] = fmaf(xv.y, w1, acc[n]);
            acc[n] = fmaf(xv.z, w2, acc[n]);
            acc[n] = fmaf(xv.w, w3, acc[n]);
        }
    }
#pragma unroll
    for (int n = 0; n < 4; n++) h[(size_t)(node0 + n) * HID + lane] = acc[n];
}

// [P|Q] = h @ [W1top-W1bot | W1bot] + [b1|0] via MFMA (layer 0 only now).
__global__ void __launch_bounds__(256) k_pq_mfma(
    const float* __restrict__ h, const float* __restrict__ W1,
    const float* __restrict__ b1, float* __restrict__ P,
    unsigned short* __restrict__ Qb, int layer) {
    int lane = threadIdx.x & 63, wave = threadIdx.x >> 6;
    int col = lane & 15, quad = lane >> 4;
    int node0 = (blockIdx.x * 4 + wave) * 16;
    if (node0 >= NN) return;
    const float* W1l = W1 + layer * 2 * HID * HID;

    bf16x8 bfr[8][2];
#pragma unroll
    for (int t = 0; t < 8; t++)
#pragma unroll
        for (int hf = 0; hf < 2; hf++) {
            uint4 u;
#pragma unroll
            for (int jp = 0; jp < 4; jp++) {
                int k0 = hf * 32 + quad * 8 + jp * 2;
                float w0, w1v;
                if (t < 4) {
                    int n = t * 16 + col;
                    w0  = W1l[k0 * HID + n] - W1l[(HID + k0) * HID + n];
                    w1v = W1l[(k0 + 1) * HID + n] - W1l[(HID + k0 + 1) * HID + n];
                } else {
                    int n = (t - 4) * 16 + col;
                    w0  = W1l[(HID + k0) * HID + n];
                    w1v = W1l[(HID + k0 + 1) * HID + n];
                }
                ((unsigned*)&u)[jp] = pk2bf(w0, w1v);
            }
            bfr[t][hf] = __builtin_bit_cast(bf16x8, u);
        }

    const float* hrow = h + (size_t)(node0 + col) * HID;
    float4 ha0 = *(const float4*)(hrow + quad * 8);
    float4 ha1 = *(const float4*)(hrow + quad * 8 + 4);
    float4 hb0 = *(const float4*)(hrow + 32 + quad * 8);
    float4 hb1 = *(const float4*)(hrow + 32 + quad * 8 + 4);
    uint4 au, bu;
    au.x = pk2bf(ha0.x, ha0.y); au.y = pk2bf(ha0.z, ha0.w);
    au.z = pk2bf(ha1.x, ha1.y); au.w = pk2bf(ha1.z, ha1.w);
    bu.x = pk2bf(hb0.x, hb0.y); bu.y = pk2bf(hb0.z, hb0.w);
    bu.z = pk2bf(hb1.x, hb1.y); bu.w = pk2bf(hb1.z, hb1.w);
    bf16x8 a0 = __builtin_bit_cast(bf16x8, au);
    bf16x8 a1 = __builtin_bit_cast(bf16x8, bu);

#pragma unroll
    for (int t = 0; t < 8; t++) {
        f32x4 c = __builtin_amdgcn_mfma_f32_16x16x32_bf16(a0, bfr[t][0], (f32x4)(0.f), 0, 0, 0);
        c = __builtin_amdgcn_mfma_f32_16x16x32_bf16(a1, bfr[t][1], c, 0, 0, 0);
        if (t < 4) {
            float bv = b1[layer * HID + t * 16 + col];
#pragma unroll
            for (int r = 0; r < 4; r++)
                P[(size_t)(node0 + quad * 4 + r) * HID + t * 16 + col] = c[r] + bv;
        } else {
#pragma unroll
            for (int r = 0; r < 4; r++)
                Qb[(size_t)(node0 + quad * 4 + r) * HID + (t - 4) * 16 + col] =
                    (unsigned short)f2bf(c[r]);
        }
    }
}

// One wave per dst node (grid-stride). Software-pipelined: next batch's csr+Q
// and next node's metadata/P/res/csr/Q issued before consuming current.
// Epilogue (dopq): wave runs PQ-MFMA for the next layer over its own hv rows
// (logged in LDS); P written in place (wave-exclusive rows), Q ping-ponged.
__global__ void __launch_bounds__(256) k_edge(
    const float* __restrict__ P, const unsigned short* __restrict__ Qb,
    const float* __restrict__ W2, const float* __restrict__ b2,
    const int* __restrict__ off, const int* __restrict__ deg,
    const unsigned short* __restrict__ csr, float* __restrict__ h,
    int layer, int nw, int E,
    int dopq, const float* __restrict__ W1n, const float* __restrict__ b1n,
    float* __restrict__ Pn, unsigned short* __restrict__ Qn,
    int fin, const float* __restrict__ Wo, const float* __restrict__ bo,
    float* __restrict__ outp) {
    __shared__ float hls[4][8][HID];  // 8 KB: per-wave hv history (<=7 nodes)
    int lane = threadIdx.x & 63;
    int col = lane & 15, quad = lane >> 4;
    int wave = threadIdx.x >> 6;
    int wid = (blockIdx.x * blockDim.x + threadIdx.x) >> 6;

    const float* W2l = W2 + layer * HID * HID;
    bf16x8 bfr[4][2];
#pragma unroll
    for (int t = 0; t < 4; t++)
#pragma unroll
        for (int hf = 0; hf < 2; hf++) {
            uint4 u;
#pragma unroll
            for (int jp = 0; jp < 4; jp++) {
                int k0 = hf * 32 + quad * 8 + jp * 2;
                ((unsigned*)&u)[jp] = pk2bf(W2l[k0 * HID + t * 16 + col],
                                            W2l[(k0 + 1) * HID + t * 16 + col]);
            }
            bfr[t][hf] = __builtin_bit_cast(bf16x8, u);
        }
    float b2v = b2[layer * HID + lane];
    float wov = fin ? Wo[lane] : 0.f;

    // prologue: state for first node
    int node = wid;
    int start = __builtin_amdgcn_readfirstlane(off[node]);
    int cnt   = __builtin_amdgcn_readfirstlane(deg[node]);
    float res = h[(size_t)node * HID + lane];
    const float4* prow = (const float4*)(P + (size_t)node * HID);
    float4 pA = prow[quad * 2], pB = prow[quad * 2 + 1];
    float4 pC = prow[8 + quad * 2], pD = prow[8 + quad * 2 + 1];
    {
        int ca = start + (col < cnt ? col : 0);
        int s0 = csr[ca < E ? ca : E - 1];
        const uint4* qr = (const uint4*)(Qb + (size_t)s0 * HID);
        // fallthrough into loop state below
        // (declared here to keep q0/q1 initialized)
        // note: cnt==0 reads clamped garbage; masked at write.
        // assignment after declarations:
        // handled right below
        (void)qr;
    }
    int ca0 = start + (col < cnt ? col : 0);
    int s0 = csr[ca0 < E ? ca0 : E - 1];
    const uint4* qr0 = (const uint4*)(Qb + (size_t)s0 * HID);
    uint4 q0 = qr0[quad], q1 = qr0[4 + quad];

    int j = 0;
    while (true) {
        f32x4 mx[4];
#pragma unroll
        for (int t = 0; t < 4; t++) mx[t] = (f32x4)(-3.4e38f);
        int b0 = 0;
        for (;;) {
            int nb = b0 + 16;
            int more = nb < cnt;
            uint4 nq0, nq1;
            if (more) {
                int idx = nb + col;
                int s2 = csr[start + (idx < cnt ? idx : nb)];
                const uint4* qr = (const uint4*)(Qb + (size_t)s2 * HID);
                nq0 = qr[quad];
                nq1 = qr[4 + quad];
            }
            uint4 a0u, a1u;
            a0u.x = pack_r(q0.x, pA.x, pA.y);
            a0u.y = pack_r(q0.y, pA.z, pA.w);
            a0u.z = pack_r(q0.z, pB.x, pB.y);
            a0u.w = pack_r(q0.w, pB.z, pB.w);
            a1u.x = pack_r(q1.x, pC.x, pC.y);
            a1u.y = pack_r(q1.y, pC.z, pC.w);
            a1u.z = pack_r(q1.z, pD.x, pD.y);
            a1u.w = pack_r(q1.w, pD.z, pD.w);
            bf16x8 a0 = __builtin_bit_cast(bf16x8, a0u);
            bf16x8 a1 = __builtin_bit_cast(bf16x8, a1u);
#pragma unroll
            for (int t = 0; t < 4; t++) {
                f32x4 c = __builtin_amdgcn_mfma_f32_16x16x32_bf16(
                    a0, bfr[t][0], (f32x4)(0.f), 0, 0, 0);
                c = __builtin_amdgcn_mfma_f32_16x16x32_bf16(a1, bfr[t][1], c, 0, 0, 0);
#pragma unroll
                for (int r = 0; r < 4; r++) mx[t][r] = fmaxf(mx[t][r], c[r]);
            }
            if (!more) break;
            q0 = nq0; q1 = nq1; b0 = nb;
        }
        // prefetch next node state before the reduction
        int nnode = node + nw;
        int nvalid = nnode < NN;
        int nstart = 0, ncnt = 0;
        float nres = 0.f;
        float4 npA, npB, npC, npD;
        uint4 nq0v, nq1v;
        if (nvalid) {
            nstart = __builtin_amdgcn_readfirstlane(off[nnode]);
            ncnt   = __builtin_amdgcn_readfirstlane(deg[nnode]);
            nres = h[(size_t)nnode * HID + lane];
            const float4* npr = (const float4*)(P + (size_t)nnode * HID);
            npA = npr[quad * 2]; npB = npr[quad * 2 + 1];
            npC = npr[8 + quad * 2]; npD = npr[8 + quad * 2 + 1];
            int ca = nstart + (col < ncnt ? col : 0);
            int s = csr[ca < E ? ca : E - 1];
            const uint4* qr = (const uint4*)(Qb + (size_t)s * HID);
            nq0v = qr[quad]; nq1v = qr[4 + quad];
        }
        // finish current node
        float outv = 0.f;
        if (cnt > 0) {
            float v[4];
#pragma unroll
            for (int t = 0; t < 4; t++) {
                v[t] = fmaxf(fmaxf(mx[t][0], mx[t][1]), fmaxf(mx[t][2], mx[t][3]));
                v[t] = fmaxf(v[t], __shfl_xor(v[t], 16, 64));
                v[t] = fmaxf(v[t], __shfl_xor(v[t], 32, 64));
            }
            float vs = quad == 0 ? v[0] : quad == 1 ? v[1] : quad == 2 ? v[2] : v[3];
            outv = fmaxf(vs + b2v, 0.f);
        }
        float hv = outv + res;
        h[(size_t)node * HID + lane] = hv;
        hls[wave][j & 7][lane] = hv;
        if (fin) {
            float v = hv * wov;
#pragma unroll
            for (int m = 32; m >= 1; m >>= 1) v += __shfl_xor(v, m, 64);
            if (lane == 0) outp[node] = v + bo[0];
        }
        j++;
        if (!nvalid) break;
        node = nnode; start = nstart; cnt = ncnt; res = nres;
        pA = npA; pB = npB; pC = npC; pD = npD;
        q0 = nq0v; q1 = nq1v;
    }

    if (dopq) {
        // next-layer PQ over this wave's j nodes (rows = node ordinal)
        bf16x8 wf[8][2];
#pragma unroll
        for (int t = 0; t < 8; t++)
#pragma unroll
            for (int hf = 0; hf < 2; hf++) {
                uint4 u;
#pragma unroll
                for (int jp = 0; jp < 4; jp++) {
                    int k0 = hf * 32 + quad * 8 + jp * 2;
                    float w0, w1v;
                    if (t < 4) {
                        int n = t * 16 + col;
                        w0  = W1n[k0 * HID + n] - W1n[(HID + k0) * HID + n];
                        w1v = W1n[(k0 + 1) * HID + n] - W1n[(HID + k0 + 1) * HID + n];
                    } else {
                        int n = (t - 4) * 16 + col;
                        w0  = W1n[(HID + k0) * HID + n];
                        w1v = W1n[(HID + k0 + 1) * HID + n];
                    }
                    ((unsigned*)&u)[jp] = pk2bf(w0, w1v);
                }
                wf[t][hf] = __builtin_bit_cast(bf16x8, u);
            }
        const float* hl = &hls[wave][col & 7][0];
        float4 ha0 = *(const float4*)(hl + quad * 8);
        float4 ha1 = *(const float4*)(hl + quad * 8 + 4);
        float4 hb0 = *(const float4*)(hl + 32 + quad * 8);
        float4 hb1 = *(const float4*)(hl + 32 + quad * 8 + 4);
        uint4 au, bu;
        au.x = pk2bf(ha0.x, ha0.y); au.y = pk2bf(ha0.z, ha0.w);
        au.z = pk2bf(ha1.x, ha1.y); au.w = pk2bf(ha1.z, ha1.w);
        bu.x = pk2bf(hb0.x, hb0.y); bu.y = pk2bf(hb0.z, hb0.w);
        bu.z = pk2bf(hb1.x, hb1.y); bu.w = pk2bf(hb1.z, hb1.w);
        bf16x8 a0 = __builtin_bit_cast(bf16x8, au);
        bf16x8 a1 = __builtin_bit_cast(bf16x8, bu);
#pragma unroll
        for (int t = 0; t < 8; t++) {
            f32x4 cinit = (f32x4)(0.f);
            float bnv = 0.f;
            if (t < 4) {
                bnv = b1n[t * 16 + col];
                cinit = (f32x4)(bnv);
            }
            f32x4 c = __builtin_amdgcn_mfma_f32_16x16x32_bf16(a0, wf[t][0], cinit, 0, 0, 0);
            c = __builtin_amdgcn_mfma_f32_16x16x32_bf16(a1, wf[t][1], c, 0, 0, 0);
#pragma unroll
            for (int r = 0; r < 4; r++) {
                int ord = quad * 4 + r;
                if (ord < j) {
                    size_t nd = (size_t)(wid + ord * nw);
                    if (t < 4)
                        Pn[nd * HID + t * 16 + col] = c[r];
                    else
                        Qn[nd * HID + (t - 4) * 16 + col] = (unsigned short)f2bf(c[r]);
                }
            }
        }
    }
}

extern "C" void kernel_launch(void* const* d_in, const int* in_sizes, int n_in,
                              void* d_out, int out_size, void* d_ws, size_t ws_size,
                              hipStream_t stream) {
    const float* x  = (const float*)d_in[0];
    const int*   ei = (const int*)d_in[1];
    const float* Wp = (const float*)d_in[2];
    const float* bp = (const float*)d_in[3];
    const float* W1 = (const float*)d_in[4];
    const float* b1 = (const float*)d_in[5];
    const float* W2 = (const float*)d_in[6];
    const float* b2 = (const float*)d_in[7];
    const float* Wo = (const float*)d_in[8];
    const float* bo = (const float*)d_in[9];
    float* out = (float*)d_out;

    const int E = in_sizes[1] / 2;
    const int N = NN;
    const int* srcp = ei;
    const int* dstp = ei + E;

    // workspace layout
    float* h  = (float*)d_ws;                       // N*HID f32
    float* Pb = h + (size_t)N * HID;                // N*HID f32
    unsigned short* Q0 = (unsigned short*)(Pb + (size_t)N * HID);  // N*HID bf16
    unsigned short* Q1 = Q0 + (size_t)N * HID;      // N*HID bf16 (ping-pong)
    int* deg    = (int*)(Q1 + (size_t)N * HID);     // N
    int* cursor = deg + N;                          // N (adjacent for one zero)
    int* off    = cursor + N;                       // N
    int* part   = off + N;                          // 256
    unsigned short* csr = (unsigned short*)(part + 256);  // E ushort

    int nbN = (N + 255) / 256;  // 196

    k_zero<<<(2 * N + 255) / 256, 256, 0, stream>>>(deg, 2 * N);
    k_count_part<<<512, 256, 0, stream>>>(dstp, deg, E);
    k_scan_partial<<<nbN, 256, 0, stream>>>(deg, part, N);
    k_scan_root<<<1, 256, 0, stream>>>(part, nbN);
    k_scan_final<<<nbN, 256, 0, stream>>>(deg, part, off, N);
    k_scatter_part<<<512, 256, 0, stream>>>(srcp, dstp, off, cursor, csr, E);

    k_proj4<<<N / 16, 256, 0, stream>>>(x, Wp, bp, h);
    const int PQ_BLOCKS = (N / 16 + 3) / 4;  // 782
    k_pq_mfma<<<PQ_BLOCKS, 256, 0, stream>>>(h, W1, b1, Pb, Q0, 0);

    const int EDGE_BLOCKS = 2048;
    const int NW = EDGE_BLOCKS * 256 / 64;
    unsigned short* Qs[2] = {Q0, Q1};
    for (int l = 0; l < NLAYERS; l++) {
        int dopq = (l < NLAYERS - 1) ? 1 : 0;
        int fin = (l == NLAYERS - 1) ? 1 : 0;
        k_edge<<<EDGE_BLOCKS, 256, 0, stream>>>(
            Pb, Qs[l & 1], W2, b2, off, deg, csr, h, l, NW, E,
            dopq, W1 + (size_t)(l + 1) * 2 * HID * HID, b1 + (size_t)(l + 1) * HID,
            Pb, Qs[(l + 1) & 1],
            fin, Wo, bo, out);
    }
}

// Round 8
// 360.062 us; speedup vs baseline: 1.1769x; 1.1769x over previous
//
#include <hip/hip_runtime.h>

#define NN 50000
#define IN_DIM 128
#define HID 64
#define NLAYERS 3
#define PART_SZ 6250  // NN/8 — one contiguous node range per XCD (blockIdx&7)

typedef __attribute__((ext_vector_type(8))) short bf16x8;
typedef __attribute__((ext_vector_type(4))) float f32x4;

__device__ __forceinline__ unsigned f2bf(float f) {
    unsigned u = __float_as_uint(f);
    return (u + 0x7fffu + ((u >> 16) & 1u)) >> 16;  // round-to-nearest-even
}

// Pack two fp32 -> packed bf16 pair (a -> lo, b -> hi), round-half-up.
__device__ __forceinline__ unsigned pk2bf(float a, float b) {
    return __builtin_amdgcn_perm(__float_as_uint(b) + 0x8000u,
                                 __float_as_uint(a) + 0x8000u, 0x07060302u);
}

// q = packed bf16 pair. Returns packed bf16 pair of relu(q + p).
__device__ __forceinline__ unsigned pack_r(unsigned q, float pA, float pB) {
    float lo = fmaxf(__uint_as_float(q << 16) + pA, 0.f);
    float hi = fmaxf(__uint_as_float(q & 0xffff0000u) + pB, 0.f);
    return pk2bf(lo, hi);
}

__global__ void k_zero(int* __restrict__ p, int n) {
    int i = blockIdx.x * blockDim.x + threadIdx.x;
    if (i < n) p[i] = 0;
}

// Partitioned degree count: block b handles dst range [(b&7)*PART_SZ, +PART_SZ).
__global__ void __launch_bounds__(256) k_count_part(const int* __restrict__ dst,
                                                    int* __restrict__ deg, int E) {
    int lo = (blockIdx.x & 7) * PART_SZ, hi = lo + PART_SZ;
    int stride = (gridDim.x >> 3) * 256;
    for (int e = (blockIdx.x >> 3) * 256 + threadIdx.x; e < E; e += stride) {
        int d = dst[e];
        if (d >= lo && d < hi) atomicAdd(&deg[d], 1);
    }
}

// 3-kernel exclusive scan over deg[N] -> off[N] (+ packed meta for k_edge)
__global__ void k_scan_partial(const int* __restrict__ deg, int* __restrict__ part, int n) {
    __shared__ int s[256];
    int i = blockIdx.x * 256 + threadIdx.x;
    s[threadIdx.x] = (i < n) ? deg[i] : 0;
    __syncthreads();
    for (int d = 128; d > 0; d >>= 1) {
        if (threadIdx.x < d) s[threadIdx.x] += s[threadIdx.x + d];
        __syncthreads();
    }
    if (threadIdx.x == 0) part[blockIdx.x] = s[0];
}

__global__ void k_scan_root(int* part, int nb) {
    __shared__ int s[256];
    int t = threadIdx.x;
    int v = (t < nb) ? part[t] : 0;
    s[t] = v;
    __syncthreads();
    for (int d = 1; d < 256; d <<= 1) {
        int add = (t >= d) ? s[t - d] : 0;
        __syncthreads();
        s[t] += add;
        __syncthreads();
    }
    if (t < nb) part[t] = s[t] - v;
}

__global__ void k_scan_final(const int* __restrict__ deg, const int* __restrict__ part,
                             int* __restrict__ off, int2* __restrict__ meta, int n) {
    __shared__ int s[256];
    int t = threadIdx.x;
    int i = blockIdx.x * 256 + t;
    int v = (i < n) ? deg[i] : 0;
    s[t] = v;
    __syncthreads();
    for (int d = 1; d < 256; d <<= 1) {
        int add = (t >= d) ? s[t - d] : 0;
        __syncthreads();
        s[t] += add;
        __syncthreads();
    }
    if (i < n) {
        int o = part[blockIdx.x] + s[t] - v;
        off[i] = o;
        meta[i] = make_int2(o, v);
    }
}

// Partitioned scatter into ushort CSR; same block->range mapping as count.
__global__ void __launch_bounds__(256) k_scatter_part(
    const int* __restrict__ src, const int* __restrict__ dst,
    const int* __restrict__ off, int* __restrict__ cursor,
    unsigned short* __restrict__ csr, int E) {
    int lo = (blockIdx.x & 7) * PART_SZ, hi = lo + PART_SZ;
    int stride = (gridDim.x >> 3) * 256;
    for (int e = (blockIdx.x >> 3) * 256 + threadIdx.x; e < E; e += stride) {
        int d = dst[e];
        if (d >= lo && d < hi) {
            int pos = atomicAdd(&cursor[d], 1);
            csr[off[d] + pos] = (unsigned short)src[e];
        }
    }
}

// h = x @ Wp + bp. Wave handles 4 nodes; weight loads amortized 4x.
__global__ void k_proj4(const float* __restrict__ x, const float* __restrict__ Wp,
                        const float* __restrict__ bp, float* __restrict__ h) {
    __shared__ float xs[4][4][IN_DIM];
    int lane = threadIdx.x & 63, wave = threadIdx.x >> 6;
    int node0 = blockIdx.x * 16 + wave * 4;
#pragma unroll
    for (int n = 0; n < 4; n++) {
        xs[wave][n][lane]      = x[(size_t)(node0 + n) * IN_DIM + lane];
        xs[wave][n][64 + lane] = x[(size_t)(node0 + n) * IN_DIM + 64 + lane];
    }
    __syncthreads();
    float bv = bp[lane];
    float acc[4] = {bv, bv, bv, bv};
#pragma unroll
    for (int k = 0; k < IN_DIM; k += 4) {
        float w0 = Wp[(k + 0) * HID + lane];
        float w1 = Wp[(k + 1) * HID + lane];
        float w2 = Wp[(k + 2) * HID + lane];
        float w3 = Wp[(k + 3) * HID + lane];
#pragma unroll
        for (int n = 0; n < 4; n++) {
            float4 xv = *(const float4*)&xs[wave][n][k];
            acc[n] = fmaf(xv.x, w0, acc[n]);
            acc[n] = fmaf(xv.y, w1, acc[n]);
            acc[n] = fmaf(xv.z, w2, acc[n]);
            acc[n] = fmaf(xv.w, w3, acc[n]);
        }
    }
#pragma unroll
    for (int n = 0; n < 4; n++) h[(size_t)(node0 + n) * HID + lane] = acc[n];
}

// [P|Q] = h @ [W1top-W1bot | W1bot] + [b1|0] via MFMA. One wave per 16 nodes.
__global__ void __launch_bounds__(256) k_pq_mfma(
    const float* __restrict__ h, const float* __restrict__ W1,
    const float* __restrict__ b1, float* __restrict__ P,
    unsigned short* __restrict__ Qb, int layer) {
    int lane = threadIdx.x & 63, wave = threadIdx.x >> 6;
    int col = lane & 15, quad = lane >> 4;
    int node0 = (blockIdx.x * 4 + wave) * 16;
    if (node0 >= NN) return;
    const float* W1l = W1 + layer * 2 * HID * HID;

    bf16x8 bfr[8][2];
#pragma unroll
    for (int t = 0; t < 8; t++)
#pragma unroll
        for (int hf = 0; hf < 2; hf++) {
            uint4 u;
#pragma unroll
            for (int jp = 0; jp < 4; jp++) {
                int k0 = hf * 32 + quad * 8 + jp * 2;
                float w0, w1v;
                if (t < 4) {
                    int n = t * 16 + col;
                    w0  = W1l[k0 * HID + n] - W1l[(HID + k0) * HID + n];
                    w1v = W1l[(k0 + 1) * HID + n] - W1l[(HID + k0 + 1) * HID + n];
                } else {
                    int n = (t - 4) * 16 + col;
                    w0  = W1l[(HID + k0) * HID + n];
                    w1v = W1l[(HID + k0 + 1) * HID + n];
                }
                ((unsigned*)&u)[jp] = pk2bf(w0, w1v);
            }
            bfr[t][hf] = __builtin_bit_cast(bf16x8, u);
        }

    const float* hrow = h + (size_t)(node0 + col) * HID;
    float4 ha0 = *(const float4*)(hrow + quad * 8);
    float4 ha1 = *(const float4*)(hrow + quad * 8 + 4);
    float4 hb0 = *(const float4*)(hrow + 32 + quad * 8);
    float4 hb1 = *(const float4*)(hrow + 32 + quad * 8 + 4);
    uint4 au, bu;
    au.x = pk2bf(ha0.x, ha0.y); au.y = pk2bf(ha0.z, ha0.w);
    au.z = pk2bf(ha1.x, ha1.y); au.w = pk2bf(ha1.z, ha1.w);
    bu.x = pk2bf(hb0.x, hb0.y); bu.y = pk2bf(hb0.z, hb0.w);
    bu.z = pk2bf(hb1.x, hb1.y); bu.w = pk2bf(hb1.z, hb1.w);
    bf16x8 a0 = __builtin_bit_cast(bf16x8, au);
    bf16x8 a1 = __builtin_bit_cast(bf16x8, bu);

#pragma unroll
    for (int t = 0; t < 8; t++) {
        f32x4 c = __builtin_amdgcn_mfma_f32_16x16x32_bf16(a0, bfr[t][0], (f32x4)(0.f), 0, 0, 0);
        c = __builtin_amdgcn_mfma_f32_16x16x32_bf16(a1, bfr[t][1], c, 0, 0, 0);
        if (t < 4) {
            float bv = b1[layer * HID + t * 16 + col];
#pragma unroll
            for (int r = 0; r < 4; r++)
                P[(size_t)(node0 + quad * 4 + r) * HID + t * 16 + col] = c[r] + bv;
        } else {
#pragma unroll
            for (int r = 0; r < 4; r++)
                Qb[(size_t)(node0 + quad * 4 + r) * HID + (t - 4) * 16 + col] =
                    (unsigned short)f2bf(c[r]);
        }
    }
}

// One wave per dst node (grid-stride). 16 edges/batch via mfma_f32_16x16x32_bf16.
// Q gather: two full-row dwordx4 instructions (8 complete 128B rows each -> one
// L2 line-touch per row instead of two), redistributed to the MFMA A layout
// through LDS (16 rows x 144B/wave; (row+seg)%8 phase schedule = conflict-free).
// Pad lanes clamp to edge b0 (valid, same-address -> coalesced broadcast).
// When fin!=0, also emit out = h@Wo+bo.
__global__ void __launch_bounds__(256) k_edge(
    const float* __restrict__ P, const unsigned short* __restrict__ Qb,
    const float* __restrict__ W2, const float* __restrict__ b2,
    const int2* __restrict__ meta, const unsigned short* __restrict__ csr,
    float* __restrict__ h, int layer, int nw,
    int fin, const float* __restrict__ Wo, const float* __restrict__ bo,
    float* __restrict__ outp) {
    __shared__ uint4 qstage[4][16][9];  // 9216B: per-wave row stage (stride 144B)
    int lane = threadIdx.x & 63;
    int col = lane & 15, quad = lane >> 4;
    int wave = threadIdx.x >> 6;
    int rrow = lane >> 3, sseg = lane & 7;  // full-row gather mapping
    int wid = (blockIdx.x * blockDim.x + threadIdx.x) >> 6;

    const float* W2l = W2 + layer * HID * HID;
    bf16x8 bfr[4][2];
#pragma unroll
    for (int t = 0; t < 4; t++)
#pragma unroll
        for (int hf = 0; hf < 2; hf++) {
            uint4 u;
#pragma unroll
            for (int jp = 0; jp < 4; jp++) {
                int k0 = hf * 32 + quad * 8 + jp * 2;
                ((unsigned*)&u)[jp] = pk2bf(W2l[k0 * HID + t * 16 + col],
                                            W2l[(k0 + 1) * HID + t * 16 + col]);
            }
            bfr[t][hf] = __builtin_bit_cast(bf16x8, u);
        }
    float b2v = b2[layer * HID + lane];
    float wov = fin ? Wo[lane] : 0.f;

    for (int node = wid; node < NN; node += nw) {
        int2 md = meta[node];
        int start = __builtin_amdgcn_readfirstlane(md.x);
        int cnt   = __builtin_amdgcn_readfirstlane(md.y);
        float res = h[(size_t)node * HID + lane];
        float outv = 0.f;
        if (cnt > 0) {
            const float4* prow = (const float4*)(P + (size_t)node * HID);
            float4 pA = prow[quad * 2], pB = prow[quad * 2 + 1];
            float4 pC = prow[8 + quad * 2], pD = prow[8 + quad * 2 + 1];
            f32x4 mx[4];
#pragma unroll
            for (int t = 0; t < 4; t++) mx[t] = (f32x4)(-3.4e38f);
            for (int b0 = 0; b0 < cnt; b0 += 16) {
                // full-row gather: lane -> (row rrow, 16B segment sseg)
                int e1 = b0 + rrow, e2 = b0 + 8 + rrow;
                int s1 = csr[start + (e1 < cnt ? e1 : b0)];
                int s2 = csr[start + (e2 < cnt ? e2 : b0)];
                uint4 v1 = ((const uint4*)(Qb + (size_t)s1 * HID))[sseg];
                uint4 v2 = ((const uint4*)(Qb + (size_t)s2 * HID))[sseg];
                qstage[wave][rrow][sseg] = v1;
                qstage[wave][8 + rrow][sseg] = v2;
                uint4 q0 = qstage[wave][col][quad];      // k in [quad*8, +8)
                uint4 q1 = qstage[wave][col][4 + quad];  // k in [32+quad*8, +8)
                uint4 a0u, a1u;
                a0u.x = pack_r(q0.x, pA.x, pA.y);
                a0u.y = pack_r(q0.y, pA.z, pA.w);
                a0u.z = pack_r(q0.z, pB.x, pB.y);
                a0u.w = pack_r(q0.w, pB.z, pB.w);
                a1u.x = pack_r(q1.x, pC.x, pC.y);
                a1u.y = pack_r(q1.y, pC.z, pC.w);
                a1u.z = pack_r(q1.z, pD.x, pD.y);
                a1u.w = pack_r(q1.w, pD.z, pD.w);
                bf16x8 a0 = __builtin_bit_cast(bf16x8, a0u);
                bf16x8 a1 = __builtin_bit_cast(bf16x8, a1u);
#pragma unroll
                for (int t = 0; t < 4; t++) {
                    f32x4 c = __builtin_amdgcn_mfma_f32_16x16x32_bf16(
                        a0, bfr[t][0], (f32x4)(0.f), 0, 0, 0);
                    c = __builtin_amdgcn_mfma_f32_16x16x32_bf16(
                        a1, bfr[t][1], c, 0, 0, 0);
#pragma unroll
                    for (int r = 0; r < 4; r++)
                        mx[t][r] = fmaxf(mx[t][r], c[r]);
                }
            }
            float v[4];
#pragma unroll
            for (int t = 0; t < 4; t++) {
                v[t] = fmaxf(fmaxf(mx[t][0], mx[t][1]), fmaxf(mx[t][2], mx[t][3]));
                v[t] = fmaxf(v[t], __shfl_xor(v[t], 16, 64));
                v[t] = fmaxf(v[t], __shfl_xor(v[t], 32, 64));
            }
            float vs = quad == 0 ? v[0] : quad == 1 ? v[1] : quad == 2 ? v[2] : v[3];
            outv = fmaxf(vs + b2v, 0.f);
        }
        float hv = outv + res;
        h[(size_t)node * HID + lane] = hv;
        if (fin) {
            float v = hv * wov;
#pragma unroll
            for (int m = 32; m >= 1; m >>= 1) v += __shfl_xor(v, m, 64);
            if (lane == 0) outp[node] = v + bo[0];
        }
    }
}

extern "C" void kernel_launch(void* const* d_in, const int* in_sizes, int n_in,
                              void* d_out, int out_size, void* d_ws, size_t ws_size,
                              hipStream_t stream) {
    const float* x  = (const float*)d_in[0];
    const int*   ei = (const int*)d_in[1];
    const float* Wp = (const float*)d_in[2];
    const float* bp = (const float*)d_in[3];
    const float* W1 = (const float*)d_in[4];
    const float* b1 = (const float*)d_in[5];
    const float* W2 = (const float*)d_in[6];
    const float* b2 = (const float*)d_in[7];
    const float* Wo = (const float*)d_in[8];
    const float* bo = (const float*)d_in[9];
    float* out = (float*)d_out;

    const int E = in_sizes[1] / 2;
    const int N = NN;
    const int* srcp = ei;
    const int* dstp = ei + E;

    // workspace layout
    float* h  = (float*)d_ws;                       // N*HID f32
    float* Pb = h + (size_t)N * HID;                // N*HID f32
    unsigned short* Qb = (unsigned short*)(Pb + (size_t)N * HID);  // N*HID bf16
    int* deg    = (int*)(Qb + (size_t)N * HID);     // N
    int* cursor = deg + N;                          // N (adjacent for one zero)
    int* off    = cursor + N;                       // N
    int* part   = off + N;                          // 256
    int2* meta  = (int2*)(part + 256);              // N
    unsigned short* csr = (unsigned short*)(meta + N);  // E ushort

    int nbN = (N + 255) / 256;  // 196

    k_zero<<<(2 * N + 255) / 256, 256, 0, stream>>>(deg, 2 * N);
    k_count_part<<<512, 256, 0, stream>>>(dstp, deg, E);
    k_scan_partial<<<nbN, 256, 0, stream>>>(deg, part, N);
    k_scan_root<<<1, 256, 0, stream>>>(part, nbN);
    k_scan_final<<<nbN, 256, 0, stream>>>(deg, part, off, meta, N);
    k_scatter_part<<<512, 256, 0, stream>>>(srcp, dstp, off, cursor, csr, E);

    k_proj4<<<N / 16, 256, 0, stream>>>(x, Wp, bp, h);
    const int EDGE_BLOCKS = 2048;
    const int NW = EDGE_BLOCKS * 256 / 64;
    const int PQ_BLOCKS = (N / 16 + 3) / 4;  // 782
    for (int l = 0; l < NLAYERS; l++) {
        k_pq_mfma<<<PQ_BLOCKS, 256, 0, stream>>>(h, W1, b1, Pb, Qb, l);
        k_edge<<<EDGE_BLOCKS, 256, 0, stream>>>(Pb, Qb, W2, b2, meta, csr, h, l, NW,
                                                l == NLAYERS - 1 ? 1 : 0, Wo, bo, out);
    }
}

// Round 9
// 351.377 us; speedup vs baseline: 1.2060x; 1.0247x over previous
//
#include <hip/hip_runtime.h>

#define NN 50000
#define IN_DIM 128
#define HID 64
#define NLAYERS 3
#define PART_SZ 6250  // NN/8 — one contiguous node range per XCD (blockIdx&7)

typedef __attribute__((ext_vector_type(8))) short bf16x8;
typedef __attribute__((ext_vector_type(4))) float f32x4;

__device__ __forceinline__ unsigned f2bf(float f) {
    unsigned u = __float_as_uint(f);
    return (u + 0x7fffu + ((u >> 16) & 1u)) >> 16;  // round-to-nearest-even
}

// Pack two fp32 -> packed bf16 pair (a -> lo, b -> hi), round-half-up.
__device__ __forceinline__ unsigned pk2bf(float a, float b) {
    return __builtin_amdgcn_perm(__float_as_uint(b) + 0x8000u,
                                 __float_as_uint(a) + 0x8000u, 0x07060302u);
}

// q = packed bf16 pair. Returns packed bf16 pair of relu(q + p).
__device__ __forceinline__ unsigned pack_r(unsigned q, float pA, float pB) {
    float lo = fmaxf(__uint_as_float(q << 16) + pA, 0.f);
    float hi = fmaxf(__uint_as_float(q & 0xffff0000u) + pB, 0.f);
    return pk2bf(lo, hi);
}

__global__ void k_zero(int* __restrict__ p, int n) {
    int i = blockIdx.x * blockDim.x + threadIdx.x;
    if (i < n) p[i] = 0;
}

// Partitioned degree count: block b handles dst range [(b&7)*PART_SZ, +PART_SZ).
__global__ void __launch_bounds__(256) k_count_part(const int* __restrict__ dst,
                                                    int* __restrict__ deg, int E) {
    int lo = (blockIdx.x & 7) * PART_SZ, hi = lo + PART_SZ;
    int stride = (gridDim.x >> 3) * 256;
    for (int e = (blockIdx.x >> 3) * 256 + threadIdx.x; e < E; e += stride) {
        int d = dst[e];
        if (d >= lo && d < hi) atomicAdd(&deg[d], 1);
    }
}

// 3-kernel exclusive scan over deg[N] -> off[N] (+ packed meta for k_edge)
__global__ void k_scan_partial(const int* __restrict__ deg, int* __restrict__ part, int n) {
    __shared__ int s[256];
    int i = blockIdx.x * 256 + threadIdx.x;
    s[threadIdx.x] = (i < n) ? deg[i] : 0;
    __syncthreads();
    for (int d = 128; d > 0; d >>= 1) {
        if (threadIdx.x < d) s[threadIdx.x] += s[threadIdx.x + d];
        __syncthreads();
    }
    if (threadIdx.x == 0) part[blockIdx.x] = s[0];
}

__global__ void k_scan_root(int* part, int nb) {
    __shared__ int s[256];
    int t = threadIdx.x;
    int v = (t < nb) ? part[t] : 0;
    s[t] = v;
    __syncthreads();
    for (int d = 1; d < 256; d <<= 1) {
        int add = (t >= d) ? s[t - d] : 0;
        __syncthreads();
        s[t] += add;
        __syncthreads();
    }
    if (t < nb) part[t] = s[t] - v;
}

__global__ void k_scan_final(const int* __restrict__ deg, const int* __restrict__ part,
                             int* __restrict__ off, int2* __restrict__ meta, int n) {
    __shared__ int s[256];
    int t = threadIdx.x;
    int i = blockIdx.x * 256 + t;
    int v = (i < n) ? deg[i] : 0;
    s[t] = v;
    __syncthreads();
    for (int d = 1; d < 256; d <<= 1) {
        int add = (t >= d) ? s[t - d] : 0;
        __syncthreads();
        s[t] += add;
        __syncthreads();
    }
    if (i < n) {
        int o = part[blockIdx.x] + s[t] - v;
        off[i] = o;
        meta[i] = make_int2(o, v);
    }
}

// Partitioned scatter into ushort CSR; same block->range mapping as count.
__global__ void __launch_bounds__(256) k_scatter_part(
    const int* __restrict__ src, const int* __restrict__ dst,
    const int* __restrict__ off, int* __restrict__ cursor,
    unsigned short* __restrict__ csr, int E) {
    int lo = (blockIdx.x & 7) * PART_SZ, hi = lo + PART_SZ;
    int stride = (gridDim.x >> 3) * 256;
    for (int e = (blockIdx.x >> 3) * 256 + threadIdx.x; e < E; e += stride) {
        int d = dst[e];
        if (d >= lo && d < hi) {
            int pos = atomicAdd(&cursor[d], 1);
            csr[off[d] + pos] = (unsigned short)src[e];
        }
    }
}

// Fused: h = x @ Wp + bp (MFMA, x cast bf16), then layer-0
// [P|Q] = h @ [W1top-W1bot | W1bot] + [b1|0] (MFMA), h staged per-wave in LDS.
// One wave per 16 nodes; 50000 = 3125 waves exactly (no partial waves).
__global__ void __launch_bounds__(256) k_projpq(
    const float* __restrict__ x, const float* __restrict__ Wp,
    const float* __restrict__ bp, const float* __restrict__ W1,
    const float* __restrict__ b1, float* __restrict__ h,
    float* __restrict__ P, unsigned short* __restrict__ Qb) {
    __shared__ float hs[4][16][66];  // 16.9 KB; stride 66 -> <=4-way b64 reads
    int lane = threadIdx.x & 63, wave = threadIdx.x >> 6;
    int col = lane & 15, quad = lane >> 4;
    int node0 = (blockIdx.x * 4 + wave) * 16;
    if (node0 >= NN) return;  // wave-uniform; no cross-wave barriers used

    // ---- stage 1: proj. B frags: bw[t][kc][j] = Wp[kc*32+quad*8+j][t*16+col]
    bf16x8 bw[4][4];
#pragma unroll
    for (int t = 0; t < 4; t++)
#pragma unroll
        for (int kc = 0; kc < 4; kc++) {
            uint4 u;
#pragma unroll
            for (int jp = 0; jp < 4; jp++) {
                int k0 = kc * 32 + quad * 8 + jp * 2;
                ((unsigned*)&u)[jp] = pk2bf(Wp[k0 * HID + t * 16 + col],
                                            Wp[(k0 + 1) * HID + t * 16 + col]);
            }
            bw[t][kc] = __builtin_bit_cast(bf16x8, u);
        }
    // A frags: x row of node0+col, k = kc*32 + quad*8 + j
    const float4* xr = (const float4*)(x + (size_t)(node0 + col) * IN_DIM);
    bf16x8 ax[4];
#pragma unroll
    for (int kc = 0; kc < 4; kc++) {
        float4 f0 = xr[kc * 8 + quad * 2], f1 = xr[kc * 8 + quad * 2 + 1];
        uint4 u;
        u.x = pk2bf(f0.x, f0.y); u.y = pk2bf(f0.z, f0.w);
        u.z = pk2bf(f1.x, f1.y); u.w = pk2bf(f1.z, f1.w);
        ax[kc] = __builtin_bit_cast(bf16x8, u);
    }
#pragma unroll
    for (int t = 0; t < 4; t++) {
        f32x4 c = (f32x4)(0.f);
#pragma unroll
        for (int kc = 0; kc < 4; kc++)
            c = __builtin_amdgcn_mfma_f32_16x16x32_bf16(ax[kc], bw[t][kc], c, 0, 0, 0);
        float bv = bp[t * 16 + col];
#pragma unroll
        for (int r = 0; r < 4; r++) {
            float hv = c[r] + bv;
            int row = quad * 4 + r;
            h[(size_t)(node0 + row) * HID + t * 16 + col] = hv;
            hs[wave][row][t * 16 + col] = hv;
        }
    }

    // ---- stage 2: layer-0 PQ. B frags from W1 (layer 0).
    bf16x8 bfr[8][2];
#pragma unroll
    for (int t = 0; t < 8; t++)
#pragma unroll
        for (int hf = 0; hf < 2; hf++) {
            uint4 u;
#pragma unroll
            for (int jp = 0; jp < 4; jp++) {
                int k0 = hf * 32 + quad * 8 + jp * 2;
                float w0, w1v;
                if (t < 4) {
                    int n = t * 16 + col;
                    w0  = W1[k0 * HID + n] - W1[(HID + k0) * HID + n];
                    w1v = W1[(k0 + 1) * HID + n] - W1[(HID + k0 + 1) * HID + n];
                } else {
                    int n = (t - 4) * 16 + col;
                    w0  = W1[(HID + k0) * HID + n];
                    w1v = W1[(HID + k0 + 1) * HID + n];
                }
                ((unsigned*)&u)[jp] = pk2bf(w0, w1v);
            }
            bfr[t][hf] = __builtin_bit_cast(bf16x8, u);
        }
    // A frags from LDS h rows (row = col, k = hf*32 + quad*8 + j)
    const float* hl = &hs[wave][col][0];
    uint4 au, bu;
    {
        float2 e0 = *(const float2*)(hl + quad * 8);
        float2 e1 = *(const float2*)(hl + quad * 8 + 2);
        float2 e2 = *(const float2*)(hl + quad * 8 + 4);
        float2 e3 = *(const float2*)(hl + quad * 8 + 6);
        au.x = pk2bf(e0.x, e0.y); au.y = pk2bf(e1.x, e1.y);
        au.z = pk2bf(e2.x, e2.y); au.w = pk2bf(e3.x, e3.y);
        float2 f0 = *(const float2*)(hl + 32 + quad * 8);
        float2 f1 = *(const float2*)(hl + 32 + quad * 8 + 2);
        float2 f2 = *(const float2*)(hl + 32 + quad * 8 + 4);
        float2 f3 = *(const float2*)(hl + 32 + quad * 8 + 6);
        bu.x = pk2bf(f0.x, f0.y); bu.y = pk2bf(f1.x, f1.y);
        bu.z = pk2bf(f2.x, f2.y); bu.w = pk2bf(f3.x, f3.y);
    }
    bf16x8 a0 = __builtin_bit_cast(bf16x8, au);
    bf16x8 a1 = __builtin_bit_cast(bf16x8, bu);
#pragma unroll
    for (int t = 0; t < 8; t++) {
        f32x4 c = __builtin_amdgcn_mfma_f32_16x16x32_bf16(a0, bfr[t][0], (f32x4)(0.f), 0, 0, 0);
        c = __builtin_amdgcn_mfma_f32_16x16x32_bf16(a1, bfr[t][1], c, 0, 0, 0);
        if (t < 4) {
            float bv = b1[t * 16 + col];
#pragma unroll
            for (int r = 0; r < 4; r++)
                P[(size_t)(node0 + quad * 4 + r) * HID + t * 16 + col] = c[r] + bv;
        } else {
#pragma unroll
            for (int r = 0; r < 4; r++)
                Qb[(size_t)(node0 + quad * 4 + r) * HID + (t - 4) * 16 + col] =
                    (unsigned short)f2bf(c[r]);
        }
    }
}

// [P|Q] = h @ [W1top-W1bot | W1bot] + [b1|0] via MFMA (layers 1,2).
__global__ void __launch_bounds__(256) k_pq_mfma(
    const float* __restrict__ h, const float* __restrict__ W1,
    const float* __restrict__ b1, float* __restrict__ P,
    unsigned short* __restrict__ Qb, int layer) {
    int lane = threadIdx.x & 63, wave = threadIdx.x >> 6;
    int col = lane & 15, quad = lane >> 4;
    int node0 = (blockIdx.x * 4 + wave) * 16;
    if (node0 >= NN) return;
    const float* W1l = W1 + layer * 2 * HID * HID;

    bf16x8 bfr[8][2];
#pragma unroll
    for (int t = 0; t < 8; t++)
#pragma unroll
        for (int hf = 0; hf < 2; hf++) {
            uint4 u;
#pragma unroll
            for (int jp = 0; jp < 4; jp++) {
                int k0 = hf * 32 + quad * 8 + jp * 2;
                float w0, w1v;
                if (t < 4) {
                    int n = t * 16 + col;
                    w0  = W1l[k0 * HID + n] - W1l[(HID + k0) * HID + n];
                    w1v = W1l[(k0 + 1) * HID + n] - W1l[(HID + k0 + 1) * HID + n];
                } else {
                    int n = (t - 4) * 16 + col;
                    w0  = W1l[(HID + k0) * HID + n];
                    w1v = W1l[(HID + k0 + 1) * HID + n];
                }
                ((unsigned*)&u)[jp] = pk2bf(w0, w1v);
            }
            bfr[t][hf] = __builtin_bit_cast(bf16x8, u);
        }

    const float* hrow = h + (size_t)(node0 + col) * HID;
    float4 ha0 = *(const float4*)(hrow + quad * 8);
    float4 ha1 = *(const float4*)(hrow + quad * 8 + 4);
    float4 hb0 = *(const float4*)(hrow + 32 + quad * 8);
    float4 hb1 = *(const float4*)(hrow + 32 + quad * 8 + 4);
    uint4 au, bu;
    au.x = pk2bf(ha0.x, ha0.y); au.y = pk2bf(ha0.z, ha0.w);
    au.z = pk2bf(ha1.x, ha1.y); au.w = pk2bf(ha1.z, ha1.w);
    bu.x = pk2bf(hb0.x, hb0.y); bu.y = pk2bf(hb0.z, hb0.w);
    bu.z = pk2bf(hb1.x, hb1.y); bu.w = pk2bf(hb1.z, hb1.w);
    bf16x8 a0 = __builtin_bit_cast(bf16x8, au);
    bf16x8 a1 = __builtin_bit_cast(bf16x8, bu);

#pragma unroll
    for (int t = 0; t < 8; t++) {
        f32x4 c = __builtin_amdgcn_mfma_f32_16x16x32_bf16(a0, bfr[t][0], (f32x4)(0.f), 0, 0, 0);
        c = __builtin_amdgcn_mfma_f32_16x16x32_bf16(a1, bfr[t][1], c, 0, 0, 0);
        if (t < 4) {
            float bv = b1[layer * HID + t * 16 + col];
#pragma unroll
            for (int r = 0; r < 4; r++)
                P[(size_t)(node0 + quad * 4 + r) * HID + t * 16 + col] = c[r] + bv;
        } else {
#pragma unroll
            for (int r = 0; r < 4; r++)
                Qb[(size_t)(node0 + quad * 4 + r) * HID + (t - 4) * 16 + col] =
                    (unsigned short)f2bf(c[r]);
        }
    }
}

// One wave per dst node (grid-stride). 16 edges/batch via mfma_f32_16x16x32_bf16.
// Q gather: two full-row dwordx4 instructions (one L2 line-touch per row),
// redistributed to MFMA A layout through an LDS row stage.
// Pad lanes clamp to edge b0 (valid). When fin!=0, also emit out = h@Wo+bo.
__global__ void __launch_bounds__(256) k_edge(
    const float* __restrict__ P, const unsigned short* __restrict__ Qb,
    const float* __restrict__ W2, const float* __restrict__ b2,
    const int2* __restrict__ meta, const unsigned short* __restrict__ csr,
    float* __restrict__ h, int layer, int nw,
    int fin, const float* __restrict__ Wo, const float* __restrict__ bo,
    float* __restrict__ outp) {
    __shared__ uint4 qstage[4][16][9];  // 9216B: per-wave row stage (stride 144B)
    int lane = threadIdx.x & 63;
    int col = lane & 15, quad = lane >> 4;
    int wave = threadIdx.x >> 6;
    int rrow = lane >> 3, sseg = lane & 7;  // full-row gather mapping
    int wid = (blockIdx.x * blockDim.x + threadIdx.x) >> 6;

    const float* W2l = W2 + layer * HID * HID;
    bf16x8 bfr[4][2];
#pragma unroll
    for (int t = 0; t < 4; t++)
#pragma unroll
        for (int hf = 0; hf < 2; hf++) {
            uint4 u;
#pragma unroll
            for (int jp = 0; jp < 4; jp++) {
                int k0 = hf * 32 + quad * 8 + jp * 2;
                ((unsigned*)&u)[jp] = pk2bf(W2l[k0 * HID + t * 16 + col],
                                            W2l[(k0 + 1) * HID + t * 16 + col]);
            }
            bfr[t][hf] = __builtin_bit_cast(bf16x8, u);
        }
    float b2v = b2[layer * HID + lane];
    float wov = fin ? Wo[lane] : 0.f;

    for (int node = wid; node < NN; node += nw) {
        int2 md = meta[node];
        int start = __builtin_amdgcn_readfirstlane(md.x);
        int cnt   = __builtin_amdgcn_readfirstlane(md.y);
        float res = h[(size_t)node * HID + lane];
        float outv = 0.f;
        if (cnt > 0) {
            const float4* prow = (const float4*)(P + (size_t)node * HID);
            float4 pA = prow[quad * 2], pB = prow[quad * 2 + 1];
            float4 pC = prow[8 + quad * 2], pD = prow[8 + quad * 2 + 1];
            f32x4 mx[4];
#pragma unroll
            for (int t = 0; t < 4; t++) mx[t] = (f32x4)(-3.4e38f);
            for (int b0 = 0; b0 < cnt; b0 += 16) {
                int e1 = b0 + rrow, e2 = b0 + 8 + rrow;
                int s1 = csr[start + (e1 < cnt ? e1 : b0)];
                int s2 = csr[start + (e2 < cnt ? e2 : b0)];
                uint4 v1 = ((const uint4*)(Qb + (size_t)s1 * HID))[sseg];
                uint4 v2 = ((const uint4*)(Qb + (size_t)s2 * HID))[sseg];
                qstage[wave][rrow][sseg] = v1;
                qstage[wave][8 + rrow][sseg] = v2;
                uint4 q0 = qstage[wave][col][quad];      // k in [quad*8, +8)
                uint4 q1 = qstage[wave][col][4 + quad];  // k in [32+quad*8, +8)
                uint4 a0u, a1u;
                a0u.x = pack_r(q0.x, pA.x, pA.y);
                a0u.y = pack_r(q0.y, pA.z, pA.w);
                a0u.z = pack_r(q0.z, pB.x, pB.y);
                a0u.w = pack_r(q0.w, pB.z, pB.w);
                a1u.x = pack_r(q1.x, pC.x, pC.y);
                a1u.y = pack_r(q1.y, pC.z, pC.w);
                a1u.z = pack_r(q1.z, pD.x, pD.y);
                a1u.w = pack_r(q1.w, pD.z, pD.w);
                bf16x8 a0 = __builtin_bit_cast(bf16x8, a0u);
                bf16x8 a1 = __builtin_bit_cast(bf16x8, a1u);
#pragma unroll
                for (int t = 0; t < 4; t++) {
                    f32x4 c = __builtin_amdgcn_mfma_f32_16x16x32_bf16(
                        a0, bfr[t][0], (f32x4)(0.f), 0, 0, 0);
                    c = __builtin_amdgcn_mfma_f32_16x16x32_bf16(
                        a1, bfr[t][1], c, 0, 0, 0);
#pragma unroll
                    for (int r = 0; r < 4; r++)
                        mx[t][r] = fmaxf(mx[t][r], c[r]);
                }
            }
            float v[4];
#pragma unroll
            for (int t = 0; t < 4; t++) {
                v[t] = fmaxf(fmaxf(mx[t][0], mx[t][1]), fmaxf(mx[t][2], mx[t][3]));
                v[t] = fmaxf(v[t], __shfl_xor(v[t], 16, 64));
                v[t] = fmaxf(v[t], __shfl_xor(v[t], 32, 64));
            }
            float vs = quad == 0 ? v[0] : quad == 1 ? v[1] : quad == 2 ? v[2] : v[3];
            outv = fmaxf(vs + b2v, 0.f);
        }
        float hv = outv + res;
        h[(size_t)node * HID + lane] = hv;
        if (fin) {
            float v = hv * wov;
#pragma unroll
            for (int m = 32; m >= 1; m >>= 1) v += __shfl_xor(v, m, 64);
            if (lane == 0) outp[node] = v + bo[0];
        }
    }
}

extern "C" void kernel_launch(void* const* d_in, const int* in_sizes, int n_in,
                              void* d_out, int out_size, void* d_ws, size_t ws_size,
                              hipStream_t stream) {
    const float* x  = (const float*)d_in[0];
    const int*   ei = (const int*)d_in[1];
    const float* Wp = (const float*)d_in[2];
    const float* bp = (const float*)d_in[3];
    const float* W1 = (const float*)d_in[4];
    const float* b1 = (const float*)d_in[5];
    const float* W2 = (const float*)d_in[6];
    const float* b2 = (const float*)d_in[7];
    const float* Wo = (const float*)d_in[8];
    const float* bo = (const float*)d_in[9];
    float* out = (float*)d_out;

    const int E = in_sizes[1] / 2;
    const int N = NN;
    const int* srcp = ei;
    const int* dstp = ei + E;

    // workspace layout
    float* h  = (float*)d_ws;                       // N*HID f32
    float* Pb = h + (size_t)N * HID;                // N*HID f32
    unsigned short* Qb = (unsigned short*)(Pb + (size_t)N * HID);  // N*HID bf16
    int* deg    = (int*)(Qb + (size_t)N * HID);     // N
    int* cursor = deg + N;                          // N (adjacent for one zero)
    int* off    = cursor + N;                       // N
    int* part   = off + N;                          // 256
    int2* meta  = (int2*)(part + 256);              // N
    unsigned short* csr = (unsigned short*)(meta + N);  // E ushort

    int nbN = (N + 255) / 256;  // 196

    k_zero<<<(2 * N + 255) / 256, 256, 0, stream>>>(deg, 2 * N);
    k_count_part<<<512, 256, 0, stream>>>(dstp, deg, E);
    k_scan_partial<<<nbN, 256, 0, stream>>>(deg, part, N);
    k_scan_root<<<1, 256, 0, stream>>>(part, nbN);
    k_scan_final<<<nbN, 256, 0, stream>>>(deg, part, off, meta, N);
    k_scatter_part<<<512, 256, 0, stream>>>(srcp, dstp, off, cursor, csr, E);

    const int PQ_BLOCKS = (N / 16 + 3) / 4;  // 782
    k_projpq<<<PQ_BLOCKS, 256, 0, stream>>>(x, Wp, bp, W1, b1, h, Pb, Qb);

    const int EDGE_BLOCKS = 2048;
    const int NW = EDGE_BLOCKS * 256 / 64;
    for (int l = 0; l < NLAYERS; l++) {
        if (l > 0)
            k_pq_mfma<<<PQ_BLOCKS, 256, 0, stream>>>(h, W1, b1, Pb, Qb, l);
        k_edge<<<EDGE_BLOCKS, 256, 0, stream>>>(Pb, Qb, W2, b2, meta, csr, h, l, NW,
                                                l == NLAYERS - 1 ? 1 : 0, Wo, bo, out);
    }
}